// Round 1
// 5379.755 us; speedup vs baseline: 1.3850x; 1.3850x over previous
//
#include <hip/hip_runtime.h>
#include <hip/hip_bf16.h>

constexpr int Bz = 32;     // batch
constexpr int Hd = 512;    // hidden
constexpr int Vv = 5000;   // vocab
constexpr int Tt = 38;     // caption length
constexpr int Ss = 37;     // outer iterations
constexpr int H3 = 1536;   // 3*H
constexpr int U  = 703;    // total sequential GRU steps
constexpr int RPB = 704;   // trajectory rows per batch (row 0 = pad/init)
constexpr int Mrows = Bz * RPB;     // 22528
constexpr int OUTC = 704;
constexpr long long OUT_MAIN = (long long)Bz * Vv * OUTC;  // 112,640,000
constexpr int NWAVE = 64;  // persistent waves in the GRU-chain kernel

typedef __attribute__((ext_vector_type(8))) short short8;   // 8 bf16
typedef __attribute__((ext_vector_type(4))) float floatx4;  // MFMA 16x16 C/D

__device__ __forceinline__ unsigned short f2bf(float f) {
    union { float f; unsigned int u; } x; x.f = f;
    unsigned int u = x.u;
    unsigned int r = u + 0x7FFFu + ((u >> 16) & 1u);  // RNE
    return (unsigned short)(r >> 16);
}

__global__ __launch_bounds__(256) void k_convert(const float* __restrict__ src,
                                                 unsigned short* __restrict__ dst, int n) {
    int i = blockIdx.x * 256 + threadIdx.x;
    if (i < n) dst[i] = f2bf(src[i]);
}

// E (s,b,h) bf16: s=0 -> embed[SOS], s>=1 -> embed[captions[b][s]]
__global__ __launch_bounds__(256) void k_embed(const float* __restrict__ tab,
                                               const int* __restrict__ cap,
                                               unsigned short* __restrict__ E, int n) {
    int i = blockIdx.x * 256 + threadIdx.x;
    if (i >= n) return;
    int h  = i & (Hd - 1);
    int sb = i >> 9;
    int b  = sb & 31;
    int s  = sb >> 5;
    int w  = (s == 0) ? 0 : cap[b * Tt + s];
    E[i] = f2bf(tab[w * Hd + h]);
}

// Writes initial state row (Ob row 0 per batch) as bf16 and resets the arrive counter.
__global__ __launch_bounds__(256) void k_init(const float* __restrict__ img,
                                              unsigned short* __restrict__ Ob,
                                              int* __restrict__ cnt) {
    int i = blockIdx.x * 256 + threadIdx.x;
    if (i == 0) *cnt = 0;
    if (i < Bz * Hd) {
        int b = i >> 9, h = i & (Hd - 1);
        Ob[(size_t)b * RPB * Hd + h] = f2bf(img[i]);
    }
}

// GI = E @ w_ih^T + b_ih   (M=1184, N=1536, K=512)
__global__ __launch_bounds__(256) void k_gemm_gi(const unsigned short* __restrict__ A,
                                                 const unsigned short* __restrict__ W,
                                                 const float* __restrict__ bias,
                                                 float* __restrict__ C) {
    constexpr int TM = (Ss * Bz) / 16;   // 74
    constexpr int TN = H3 / 16;          // 96
    int wid = blockIdx.x * 4 + (threadIdx.x >> 6);
    if (wid >= TM * TN) return;
    int tm = wid % TM, tn = wid / TM;
    int lane = threadIdx.x & 63;
    int col = lane & 15, quad = lane >> 4;

    const short8* Ap = (const short8*)(A + (size_t)(tm * 16 + col) * Hd + quad * 8);
    const short8* Wp = (const short8*)(W + (size_t)(tn * 16 + col) * Hd + quad * 8);
    floatx4 acc = {0.f, 0.f, 0.f, 0.f};
#pragma unroll
    for (int k = 0; k < 16; k++)
        acc = __builtin_amdgcn_mfma_f32_16x16x32_bf16(Ap[k * 4], Wp[k * 4], acc, 0, 0, 0);
    int n = tn * 16 + col;
    float bn = bias[n];
#pragma unroll
    for (int i = 0; i < 4; i++) {
        int m = tm * 16 + quad * 4 + i;
        C[m * H3 + n] = acc[i] + bn;
    }
}

// Persistent GRU chain: 64 waves (one per WG), all 703 steps in one launch.
// Wave (mt, jt): batch rows mt*16..+16, h-columns jt*16..+16 (gemm cols {j, j+512, j+1024}).
// W_hh fragments resident in VGPRs; fp32 h carried in registers; bf16 h broadcast via Ob
// rows (monotonic row index -> no WAR hazard; one release+arrive / acquire+poll per step).
__global__ __launch_bounds__(64, 1) void k_gru_chain(const unsigned short* __restrict__ Whh,
                                                     const float* __restrict__ GI,
                                                     const float* __restrict__ bhh,
                                                     const float* __restrict__ img,
                                                     unsigned short* __restrict__ Ob,
                                                     float* __restrict__ hout,
                                                     int* cnt) {
    const int lane = threadIdx.x;        // 64 threads = 1 wave
    const int col  = lane & 15;
    const int quad = lane >> 4;
    const int wid  = blockIdx.x;         // 0..63
    const int mt   = wid & 1;
    const int jt   = wid >> 1;           // 0..31
    const int j    = jt * 16 + col;

    // Resident B fragments: W_hh rows {j, j+512, j+1024}, all 16 K-chunks. 192 VGPRs.
    short8 Wf[3][16];
#pragma unroll
    for (int g = 0; g < 3; ++g) {
        const unsigned short* wrp = Whh + (size_t)(g * 512 + j) * Hd + quad * 8;
#pragma unroll
        for (int kk = 0; kk < 16; ++kk)
            Wf[g][kk] = *(const short8*)(wrp + kk * 32);
    }

    const float br = bhh[j], bz = bhh[j + 512], bn = bhh[j + 1024];

    // fp32 hidden state carried in registers (C-fragment layout), init from img_feat.
    float hp[4];
#pragma unroll
    for (int i = 0; i < 4; ++i)
        hp[i] = img[(mt * 16 + quad * 4 + i) * Hd + j];

    int s = 0, it = 0;
    for (int u = 0; u < U; ++u) {
        if (u) {
            const int target = NWAVE * u;   // all waves finished step u-1 -> row u complete
            int guard = 1 << 22;            // loud abort instead of hang if protocol breaks
            for (;;) {
                int c0 = 0;
                if (lane == 0)
                    c0 = __hip_atomic_load(cnt, __ATOMIC_RELAXED, __HIP_MEMORY_SCOPE_AGENT);
                c0 = __builtin_amdgcn_readfirstlane(c0);
                if (c0 >= target) break;
                if (--guard == 0) return;
                __builtin_amdgcn_s_sleep(1);
            }
            __builtin_amdgcn_fence(__ATOMIC_ACQUIRE, "agent");
        }

        // GI loads for this step (issued early; latency hides under A-loads + MFMA)
        const float* gp = GI + (size_t)s * (Bz * H3) + (size_t)(mt * 16 + quad * 4) * H3 + j;
        float gv[12];
#pragma unroll
        for (int g = 0; g < 3; ++g)
#pragma unroll
            for (int i = 0; i < 4; ++i)
                gv[g * 4 + i] = gp[(size_t)i * H3 + g * 512];

        // A fragments: bf16 state row u (row 0 = img, pre-written by k_init)
        const unsigned short* ar = Ob + ((size_t)(mt * 16 + col) * RPB + u) * Hd + quad * 8;
        short8 Af[16];
#pragma unroll
        for (int kk = 0; kk < 16; ++kk)
            Af[kk] = *(const short8*)(ar + kk * 32);

        floatx4 aR = {0.f,0.f,0.f,0.f}, aZ = {0.f,0.f,0.f,0.f}, aN = {0.f,0.f,0.f,0.f};
#pragma unroll
        for (int kk = 0; kk < 16; ++kk) {
            aR = __builtin_amdgcn_mfma_f32_16x16x32_bf16(Af[kk], Wf[0][kk], aR, 0, 0, 0);
            aZ = __builtin_amdgcn_mfma_f32_16x16x32_bf16(Af[kk], Wf[1][kk], aZ, 0, 0, 0);
            aN = __builtin_amdgcn_mfma_f32_16x16x32_bf16(Af[kk], Wf[2][kk], aN, 0, 0, 0);
        }

        unsigned short* wrow = Ob + (size_t)(u + 1) * Hd + j;
#pragma unroll
        for (int i = 0; i < 4; ++i) {
            const int b = mt * 16 + quad * 4 + i;
            float r  = 1.f / (1.f + __expf(-(gv[i]     + aR[i] + br)));
            float z  = 1.f / (1.f + __expf(-(gv[4 + i] + aZ[i] + bz)));
            float nn = tanhf(gv[8 + i] + r * (aN[i] + bn));
            float hn = (1.f - z) * nn + z * hp[i];
            hp[i] = hn;
            wrow[(size_t)b * RPB * Hd] = f2bf(hn);
        }

        // Release (vmcnt drain + L2 writeback) then arrive.
        __builtin_amdgcn_fence(__ATOMIC_RELEASE, "agent");
        if (lane == 0)
            __hip_atomic_fetch_add(cnt, 1, __ATOMIC_RELAXED, __HIP_MEMORY_SCOPE_AGENT);

        if (++s > it) { s = 0; ++it; }
    }

    // Final fp32 hidden -> out tail
#pragma unroll
    for (int i = 0; i < 4; ++i)
        hout[(mt * 16 + quad * 4 + i) * Hd + j] = hp[i];
}

// Projection: out[b][v][c] = Ob_row(b,c) . proj_w[v] + proj_b[v]; c=0 -> one-hot(v==0).
__global__ __launch_bounds__(256) void k_proj(const unsigned short* __restrict__ A,
                                              const unsigned short* __restrict__ W,
                                              const float* __restrict__ pb,
                                              float* __restrict__ out) {
    __shared__ unsigned short As[128 * 40];   // +8 shorts pad per row: conflict-free b128
    __shared__ unsigned short Bs[128 * 40];
    int bx = blockIdx.x;
    int bn = bx % 40, bm = bx / 40;           // consecutive blocks share the A tile
    int m0 = bm * 128, n0 = bn * 128;
    int tid = threadIdx.x;
    int w = tid >> 6, lane = tid & 63;
    int wm = w & 1, wn = w >> 1;
    int col = lane & 15, quad = lane >> 4;

    floatx4 acc[4][4] = {};
    for (int kb = 0; kb < 16; ++kb) {
        int k0 = kb * 32;
        __syncthreads();
        for (int q = tid; q < 512; q += 256) {
            int row = q >> 2, kp = (q & 3) << 3;
            *(short8*)&As[row * 40 + kp] =
                *(const short8*)(A + (size_t)(m0 + row) * Hd + k0 + kp);
            int vr = n0 + row; if (vr >= Vv) vr = Vv - 1;
            *(short8*)&Bs[row * 40 + kp] =
                *(const short8*)(W + (size_t)vr * Hd + k0 + kp);
        }
        __syncthreads();
        short8 af[4], bf[4];
#pragma unroll
        for (int i = 0; i < 4; ++i) {
            af[i] = *(const short8*)&As[(wm * 64 + i * 16 + col) * 40 + quad * 8];
            bf[i] = *(const short8*)&Bs[(wn * 64 + i * 16 + col) * 40 + quad * 8];
        }
#pragma unroll
        for (int mi = 0; mi < 4; ++mi)
#pragma unroll
            for (int ni = 0; ni < 4; ++ni)
                acc[mi][ni] = __builtin_amdgcn_mfma_f32_16x16x32_bf16(af[mi], bf[ni],
                                                                      acc[mi][ni], 0, 0, 0);
    }
#pragma unroll
    for (int mi = 0; mi < 4; ++mi) {
        int r0l = m0 + wm * 64 + mi * 16 + quad * 4;  // aligned 4-row group, one b
        int b  = r0l / RPB;
        int cm = r0l - b * RPB;                       // multiple of 4
#pragma unroll
        for (int ni = 0; ni < 4; ++ni) {
            int v = n0 + wn * 64 + ni * 16 + col;
            if (v >= Vv) continue;
            float bias = pb[v];
            floatx4 a = acc[mi][ni];
            float4 val;
            val.x = a[0] + bias; val.y = a[1] + bias;
            val.z = a[2] + bias; val.w = a[3] + bias;
            if (cm == 0) val.x = (v == 0) ? 1.f : 0.f;   // fold one-hot column
            *(float4*)(out + ((size_t)(b * Vv + v)) * OUTC + cm) = val;
        }
    }
}

extern "C" void kernel_launch(void* const* d_in, const int* in_sizes, int n_in,
                              void* d_out, int out_size, void* d_ws, size_t ws_size,
                              hipStream_t stream) {
    const float* img = (const float*)d_in[0];
    const int*   cap = (const int*)d_in[1];
    const float* tab = (const float*)d_in[2];
    const float* wih = (const float*)d_in[3];
    const float* whh = (const float*)d_in[4];
    const float* bih = (const float*)d_in[5];
    const float* bhh = (const float*)d_in[6];
    const float* pw  = (const float*)d_in[7];
    const float* pb  = (const float*)d_in[8];
    float* out = (float*)d_out;

    char* wp = (char*)d_ws;
    auto alloc = [&](size_t bytes) {
        char* p = wp;
        wp += (bytes + 511) & ~(size_t)511;
        return p;
    };
    unsigned short* Eb   = (unsigned short*)alloc((size_t)Ss * Bz * Hd * 2);
    unsigned short* wihb = (unsigned short*)alloc((size_t)H3 * Hd * 2);
    unsigned short* whhb = (unsigned short*)alloc((size_t)H3 * Hd * 2);
    unsigned short* pwb  = (unsigned short*)alloc((size_t)Vv * Hd * 2);
    float*          GI   = (float*)alloc((size_t)Ss * Bz * H3 * 4);
    unsigned short* Ob   = (unsigned short*)alloc((size_t)Mrows * Hd * 2);
    int*            cnt  = (int*)alloc(sizeof(int));

    k_convert<<<(H3 * Hd + 255) / 256, 256, 0, stream>>>(wih, wihb, H3 * Hd);
    k_convert<<<(H3 * Hd + 255) / 256, 256, 0, stream>>>(whh, whhb, H3 * Hd);
    k_convert<<<(Vv * Hd + 255) / 256, 256, 0, stream>>>(pw, pwb, Vv * Hd);
    k_embed<<<(Ss * Bz * Hd + 255) / 256, 256, 0, stream>>>(tab, cap, Eb, Ss * Bz * Hd);
    k_init<<<(Bz * Hd + 255) / 256, 256, 0, stream>>>(img, Ob, cnt);

    k_gemm_gi<<<(74 * 96) / 4, 256, 0, stream>>>(Eb, wihb, bih, GI);

    // All 703 sequential GRU steps in ONE persistent kernel (64 co-resident waves).
    k_gru_chain<<<NWAVE, 64, 0, stream>>>(whhb, GI, bhh, img, Ob, out + OUT_MAIN, cnt);

    k_proj<<<176 * 40, 256, 0, stream>>>(Ob, pwb, pb, out);
}

// Round 2
// 3890.246 us; speedup vs baseline: 1.9153x; 1.3829x over previous
//
#include <hip/hip_runtime.h>
#include <hip/hip_bf16.h>

constexpr int Bz = 32;     // batch
constexpr int Hd = 512;    // hidden
constexpr int Vv = 5000;   // vocab
constexpr int Tt = 38;     // caption length
constexpr int Ss = 37;     // outer iterations
constexpr int H3 = 1536;   // 3*H
constexpr int U  = 703;    // total sequential GRU steps
constexpr int RPB = 704;   // trajectory rows per batch (row 0 = pad/init)
constexpr int Mrows = Bz * RPB;     // 22528
constexpr int OUTC = 704;
constexpr long long OUT_MAIN = (long long)Bz * Vv * OUTC;  // 112,640,000
constexpr int NWAVE = 64;  // persistent waves in the GRU-chain kernel

typedef __attribute__((ext_vector_type(8))) short short8;   // 8 bf16
typedef __attribute__((ext_vector_type(4))) float floatx4;  // MFMA 16x16 C/D

__device__ __forceinline__ unsigned short f2bf(float f) {
    union { float f; unsigned int u; } x; x.f = f;
    unsigned int u = x.u;
    unsigned int r = u + 0x7FFFu + ((u >> 16) & 1u);  // RNE
    return (unsigned short)(r >> 16);
}

__global__ __launch_bounds__(256) void k_convert(const float* __restrict__ src,
                                                 unsigned short* __restrict__ dst, int n) {
    int i = blockIdx.x * 256 + threadIdx.x;
    if (i < n) dst[i] = f2bf(src[i]);
}

// E (s,b,h) bf16: s=0 -> embed[SOS], s>=1 -> embed[captions[b][s]]
__global__ __launch_bounds__(256) void k_embed(const float* __restrict__ tab,
                                               const int* __restrict__ cap,
                                               unsigned short* __restrict__ E, int n) {
    int i = blockIdx.x * 256 + threadIdx.x;
    if (i >= n) return;
    int h  = i & (Hd - 1);
    int sb = i >> 9;
    int b  = sb & 31;
    int s  = sb >> 5;
    int w  = (s == 0) ? 0 : cap[b * Tt + s];
    E[i] = f2bf(tab[w * Hd + h]);
}

// Initial state row (Ob row 0 per batch) as bf16; zero the 64 arrive flags.
// Kernel-end implicit release flushes these to LLC before the chain starts.
__global__ __launch_bounds__(256) void k_init(const float* __restrict__ img,
                                              unsigned short* __restrict__ Ob,
                                              int* __restrict__ flags) {
    int i = blockIdx.x * 256 + threadIdx.x;
    if (i < NWAVE) flags[i] = 0;
    if (i < Bz * Hd) {
        int b = i >> 9, h = i & (Hd - 1);
        Ob[(size_t)b * RPB * Hd + h] = f2bf(img[i]);
    }
}

// GI = E @ w_ih^T + b_ih   (M=1184, N=1536, K=512)
__global__ __launch_bounds__(256) void k_gemm_gi(const unsigned short* __restrict__ A,
                                                 const unsigned short* __restrict__ W,
                                                 const float* __restrict__ bias,
                                                 float* __restrict__ C) {
    constexpr int TM = (Ss * Bz) / 16;   // 74
    constexpr int TN = H3 / 16;          // 96
    int wid = blockIdx.x * 4 + (threadIdx.x >> 6);
    if (wid >= TM * TN) return;
    int tm = wid % TM, tn = wid / TM;
    int lane = threadIdx.x & 63;
    int col = lane & 15, quad = lane >> 4;

    const short8* Ap = (const short8*)(A + (size_t)(tm * 16 + col) * Hd + quad * 8);
    const short8* Wp = (const short8*)(W + (size_t)(tn * 16 + col) * Hd + quad * 8);
    floatx4 acc = {0.f, 0.f, 0.f, 0.f};
#pragma unroll
    for (int k = 0; k < 16; k++)
        acc = __builtin_amdgcn_mfma_f32_16x16x32_bf16(Ap[k * 4], Wp[k * 4], acc, 0, 0, 0);
    int n = tn * 16 + col;
    float bn = bias[n];
#pragma unroll
    for (int i = 0; i < 4; i++) {
        int m = tm * 16 + quad * 4 + i;
        C[m * H3 + n] = acc[i] + bn;
    }
}

// Persistent GRU chain: 64 waves (one per WG), all 703 steps in one launch.
// Fence-free LLC-coherent protocol:
//  - h broadcast written with relaxed AGENT atomic u32 stores (sc-flagged -> straight
//    to LLC, no dirty L2 lines anywhere) and read with relaxed AGENT atomic u64 loads.
//  - arrive = own s_waitcnt vmcnt(0) + monotonic flag store (no RMW contention).
//  - NO acquire/release fences -> no buffer_inv/buffer_wbl2 -> GI/weights stay L2-warm.
//  - two independent sync domains (batch halves mt=0/1): wave (mt,jt) only reads rows
//    written by its own domain. Domain flags are contiguous (one cache line each).
__global__ __launch_bounds__(64, 1) void k_gru_chain(const unsigned short* __restrict__ Whh,
                                                     const float* __restrict__ GI,
                                                     const float* __restrict__ bhh,
                                                     const float* __restrict__ img,
                                                     unsigned short* __restrict__ Ob,
                                                     float* __restrict__ hout,
                                                     int* __restrict__ flags) {
    const int lane = threadIdx.x;        // 64 threads = 1 wave
    const int col  = lane & 15;
    const int quad = lane >> 4;
    const int wid  = blockIdx.x;         // 0..63
    const int mt   = wid & 1;
    const int jt   = wid >> 1;           // 0..31
    const int j    = jt * 16 + col;

    // Resident B fragments: W_hh rows {j, j+512, j+1024}, all 16 K-chunks.
    short8 Wf[3][16];
#pragma unroll
    for (int g = 0; g < 3; ++g) {
        const unsigned short* wrp = Whh + (size_t)(g * 512 + j) * Hd + quad * 8;
#pragma unroll
        for (int kk = 0; kk < 16; ++kk)
            Wf[g][kk] = *(const short8*)(wrp + kk * 32);
    }

    const float br = bhh[j], bz = bhh[j + 512], bn = bhh[j + 1024];

    // fp32 hidden state carried in registers (C-fragment layout), init from img_feat.
    float hp[4];
#pragma unroll
    for (int i = 0; i < 4; ++i)
        hp[i] = img[(mt * 16 + quad * 4 + i) * Hd + j];

    const int myFlag   = mt * 32 + jt;            // arrive slot
    const int pollFlag = mt * 32 + (lane & 31);   // this lane polls one domain flag

    int s = 0, it = 0;
    for (int u = 0; u < U; ++u) {
        // GI loads for this step: always valid, L2-warm; latency hides under the spin.
        const float* gp = GI + (size_t)s * (Bz * H3) + (size_t)(mt * 16 + quad * 4) * H3 + j;
        float gv[12];
#pragma unroll
        for (int g = 0; g < 3; ++g)
#pragma unroll
            for (int i = 0; i < 4; ++i)
                gv[g * 4 + i] = gp[(size_t)i * H3 + g * 512];

        if (u) {
            int guard = 1 << 22;    // loud(ish) abort instead of infinite hang
            for (;;) {
                int v = __hip_atomic_load(&flags[pollFlag], __ATOMIC_RELAXED,
                                          __HIP_MEMORY_SCOPE_AGENT);
                if (__all(v >= u)) break;
                if (--guard == 0) return;
                __builtin_amdgcn_s_sleep(1);
            }
            asm volatile("" ::: "memory");   // don't hoist data loads above the poll
        }

        // A fragments: bf16 state row u via LLC-coherent loads (bypass stale L2).
        const unsigned long long* ar =
            (const unsigned long long*)(Ob + ((size_t)(mt * 16 + col) * RPB + u) * Hd) +
            quad * 2;
        short8 Af[16];
#pragma unroll
        for (int kk = 0; kk < 16; ++kk) {
            union { unsigned long long q[2]; short8 v; } t;
            t.q[0] = __hip_atomic_load(ar + kk * 8, __ATOMIC_RELAXED,
                                       __HIP_MEMORY_SCOPE_AGENT);
            t.q[1] = __hip_atomic_load(ar + kk * 8 + 1, __ATOMIC_RELAXED,
                                       __HIP_MEMORY_SCOPE_AGENT);
            Af[kk] = t.v;
        }

        floatx4 aR = {0.f,0.f,0.f,0.f}, aZ = {0.f,0.f,0.f,0.f}, aN = {0.f,0.f,0.f,0.f};
#pragma unroll
        for (int kk = 0; kk < 16; ++kk) {
            aR = __builtin_amdgcn_mfma_f32_16x16x32_bf16(Af[kk], Wf[0][kk], aR, 0, 0, 0);
            aZ = __builtin_amdgcn_mfma_f32_16x16x32_bf16(Af[kk], Wf[1][kk], aZ, 0, 0, 0);
            aN = __builtin_amdgcn_mfma_f32_16x16x32_bf16(Af[kk], Wf[2][kk], aN, 0, 0, 0);
        }

        unsigned short hb[4];
#pragma unroll
        for (int i = 0; i < 4; ++i) {
            float r  = 1.f / (1.f + __expf(-(gv[i]     + aR[i] + br)));
            float z  = 1.f / (1.f + __expf(-(gv[4 + i] + aZ[i] + bz)));
            float nn = tanhf(gv[8 + i] + r * (aN[i] + bn));
            float hn = (1.f - z) * nn + z * hp[i];
            hp[i] = hn;
            hb[i] = f2bf(hn);
        }

        // Pack column pairs to u32 (16-bit atomics would CAS-loop) and store via LLC.
        // Lane bit0 == col bit0, so lane^1 is the column partner with the same rows.
#pragma unroll
        for (int i = 0; i < 4; ++i) {
            int ox = __shfl_xor((int)hb[i], 1);
            unsigned w32 = (col & 1) ? (((unsigned)ox & 0xFFFFu) | ((unsigned)hb[i] << 16))
                                     : (((unsigned)hb[i] & 0xFFFFu) | ((unsigned)ox << 16));
            bool storeIt = (col & 1) ? (i >= 2) : (i < 2);
            if (storeIt) {
                int b = mt * 16 + quad * 4 + i;
                unsigned* p = (unsigned*)(Ob + ((size_t)b * RPB + (u + 1)) * Hd + (j & ~1));
                __hip_atomic_store(p, w32, __ATOMIC_RELAXED, __HIP_MEMORY_SCOPE_AGENT);
            }
        }

        // Own stores at LLC, then publish (monotonic flag store, no RMW).
        asm volatile("s_waitcnt vmcnt(0)" ::: "memory");
        if (lane == 0)
            __hip_atomic_store(&flags[myFlag], u + 1, __ATOMIC_RELAXED,
                               __HIP_MEMORY_SCOPE_AGENT);

        if (++s > it) { s = 0; ++it; }
    }

    // Final fp32 hidden -> out tail (kernel-end implicit release flushes it).
#pragma unroll
    for (int i = 0; i < 4; ++i)
        hout[(mt * 16 + quad * 4 + i) * Hd + j] = hp[i];
}

// Projection: out[b][v][c] = Ob_row(b,c) . proj_w[v] + proj_b[v]; c=0 -> one-hot(v==0).
__global__ __launch_bounds__(256) void k_proj(const unsigned short* __restrict__ A,
                                              const unsigned short* __restrict__ W,
                                              const float* __restrict__ pb,
                                              float* __restrict__ out) {
    __shared__ unsigned short As[128 * 40];   // +8 shorts pad per row: conflict-free b128
    __shared__ unsigned short Bs[128 * 40];
    int bx = blockIdx.x;
    int bn = bx % 40, bm = bx / 40;           // consecutive blocks share the A tile
    int m0 = bm * 128, n0 = bn * 128;
    int tid = threadIdx.x;
    int w = tid >> 6, lane = tid & 63;
    int wm = w & 1, wn = w >> 1;
    int col = lane & 15, quad = lane >> 4;

    floatx4 acc[4][4] = {};
    for (int kb = 0; kb < 16; ++kb) {
        int k0 = kb * 32;
        __syncthreads();
        for (int q = tid; q < 512; q += 256) {
            int row = q >> 2, kp = (q & 3) << 3;
            *(short8*)&As[row * 40 + kp] =
                *(const short8*)(A + (size_t)(m0 + row) * Hd + k0 + kp);
            int vr = n0 + row; if (vr >= Vv) vr = Vv - 1;
            *(short8*)&Bs[row * 40 + kp] =
                *(const short8*)(W + (size_t)vr * Hd + k0 + kp);
        }
        __syncthreads();
        short8 af[4], bf[4];
#pragma unroll
        for (int i = 0; i < 4; ++i) {
            af[i] = *(const short8*)&As[(wm * 64 + i * 16 + col) * 40 + quad * 8];
            bf[i] = *(const short8*)&Bs[(wn * 64 + i * 16 + col) * 40 + quad * 8];
        }
#pragma unroll
        for (int mi = 0; mi < 4; ++mi)
#pragma unroll
            for (int ni = 0; ni < 4; ++ni)
                acc[mi][ni] = __builtin_amdgcn_mfma_f32_16x16x32_bf16(af[mi], bf[ni],
                                                                      acc[mi][ni], 0, 0, 0);
    }
#pragma unroll
    for (int mi = 0; mi < 4; ++mi) {
        int r0l = m0 + wm * 64 + mi * 16 + quad * 4;  // aligned 4-row group, one b
        int b  = r0l / RPB;
        int cm = r0l - b * RPB;                       // multiple of 4
#pragma unroll
        for (int ni = 0; ni < 4; ++ni) {
            int v = n0 + wn * 64 + ni * 16 + col;
            if (v >= Vv) continue;
            float bias = pb[v];
            floatx4 a = acc[mi][ni];
            float4 val;
            val.x = a[0] + bias; val.y = a[1] + bias;
            val.z = a[2] + bias; val.w = a[3] + bias;
            if (cm == 0) val.x = (v == 0) ? 1.f : 0.f;   // fold one-hot column
            *(float4*)(out + ((size_t)(b * Vv + v)) * OUTC + cm) = val;
        }
    }
}

extern "C" void kernel_launch(void* const* d_in, const int* in_sizes, int n_in,
                              void* d_out, int out_size, void* d_ws, size_t ws_size,
                              hipStream_t stream) {
    const float* img = (const float*)d_in[0];
    const int*   cap = (const int*)d_in[1];
    const float* tab = (const float*)d_in[2];
    const float* wih = (const float*)d_in[3];
    const float* whh = (const float*)d_in[4];
    const float* bih = (const float*)d_in[5];
    const float* bhh = (const float*)d_in[6];
    const float* pw  = (const float*)d_in[7];
    const float* pb  = (const float*)d_in[8];
    float* out = (float*)d_out;

    char* wp = (char*)d_ws;
    auto alloc = [&](size_t bytes) {
        char* p = wp;
        wp += (bytes + 511) & ~(size_t)511;
        return p;
    };
    unsigned short* Eb   = (unsigned short*)alloc((size_t)Ss * Bz * Hd * 2);
    unsigned short* wihb = (unsigned short*)alloc((size_t)H3 * Hd * 2);
    unsigned short* whhb = (unsigned short*)alloc((size_t)H3 * Hd * 2);
    unsigned short* pwb  = (unsigned short*)alloc((size_t)Vv * Hd * 2);
    float*          GI   = (float*)alloc((size_t)Ss * Bz * H3 * 4);
    unsigned short* Ob   = (unsigned short*)alloc((size_t)Mrows * Hd * 2);
    int*            flags= (int*)alloc(NWAVE * sizeof(int));

    k_convert<<<(H3 * Hd + 255) / 256, 256, 0, stream>>>(wih, wihb, H3 * Hd);
    k_convert<<<(H3 * Hd + 255) / 256, 256, 0, stream>>>(whh, whhb, H3 * Hd);
    k_convert<<<(Vv * Hd + 255) / 256, 256, 0, stream>>>(pw, pwb, Vv * Hd);
    k_embed<<<(Ss * Bz * Hd + 255) / 256, 256, 0, stream>>>(tab, cap, Eb, Ss * Bz * Hd);
    k_init<<<(Bz * Hd + 255) / 256, 256, 0, stream>>>(img, Ob, flags);

    k_gemm_gi<<<(74 * 96) / 4, 256, 0, stream>>>(Eb, wihb, bih, GI);

    // All 703 sequential GRU steps in ONE persistent kernel (64 co-resident waves).
    k_gru_chain<<<NWAVE, 64, 0, stream>>>(whhb, GI, bhh, img, Ob, out + OUT_MAIN, flags);

    k_proj<<<176 * 40, 256, 0, stream>>>(Ob, pwb, pb, out);
}